// Round 10
// baseline (101.570 us; speedup 1.0000x reference)
//
#include <hip/hip_runtime.h>
#include <hip/hip_bf16.h>

#define OUTN 11008
#define KDIM 4096
#define BDIM 32
#define NT16 688          // OUTN / 16
#define WCOUNT 45088768   // OUTN * KDIM
#define PF   8            // software-pipeline depth (power of 2)
#define NPB  1024         // prep blocks / partials
#define DLO  0.0069400f   // conservative delta band: delta_expected = 6.9759e-3 (+-40 sigma)
#define DHI  0.0070115f

typedef __bf16 bf16x8 __attribute__((ext_vector_type(8)));
typedef float f32x4  __attribute__((ext_vector_type(4)));
typedef float f32x16 __attribute__((ext_vector_type(16)));

__device__ __forceinline__ ushort f2bf(float f) {
    unsigned u = __builtin_bit_cast(unsigned, f);
    u = (u + 0x7FFFu + ((u >> 16) & 1u)) >> 16;
    return (ushort)u;
}

// ternary as f32 bits: sign(w)*1.0f if |w|>d else 0 (raw fallback path)
__device__ __forceinline__ unsigned tern1(float w, float d) {
    unsigned b = __builtin_bit_cast(unsigned, w);
    unsigned s = (b & 0x80000000u) | 0x3F800000u;
    return (__builtin_fabsf(w) > d) ? s : 0u;
}
__device__ __forceinline__ unsigned ternpack(float a, float b, float d) {
    return __builtin_amdgcn_perm(tern1(b, d), tern1(a, d), 0x07060302u);
}

__device__ __forceinline__ float delta_fix(double delta_d) {
    float dc = (float)delta_d;
    if ((double)dc > delta_d)          // largest f32 <= delta_f64
        dc = __builtin_bit_cast(float, __builtin_bit_cast(unsigned, dc) - 1u);
    return dc;
}

// decode crumb pair (elems 2j, 2j+1) of 16-bit code word -> u32 of 2 bf16
// codes: 0 -> 0x0000, 1 -> 0x3F80 (+1), 2 -> 0xBF80 (-1), 3(EXC) -> 0x0000
__device__ __forceinline__ unsigned dec2(unsigned c, int j) {
    unsigned c0 = (c >> (4 * j)) & 3u;
    unsigned c1 = (c >> (4 * j + 2)) & 3u;
    unsigned m = c0 | (c1 << 16);
    unsigned sel = m + (m << 8) + 0x04000400u;
    return __builtin_amdgcn_perm(0x00BF3F00u, 0x00808000u, sel);
}

// ---- pass 1: abssum partials + 2-bit ternary codes + exception buckets + x conv ----
__global__ __launch_bounds__(256) void prep_k(const float4* __restrict__ w4,
                                              const float* __restrict__ x,
                                              ushort* __restrict__ xb,
                                              float* __restrict__ xT,
                                              unsigned char* __restrict__ codes,
                                              unsigned* __restrict__ cnt,
                                              uint2* __restrict__ ebuf,
                                              double* __restrict__ dpart) {
    const int tid = blockIdx.x * 256 + threadIdx.x;    // grid fixed at NPB blocks

    // x f32 -> bf16 fragment-ordered [K/8][32][8] + f32 transposed copy xT[4096][32]
    if (threadIdx.x < 32) {
        const int i4 = blockIdx.x * 32 + threadIdx.x;  // 0..32767
        const int elem = i4 * 4;
        const int b = elem >> 12;
        const int k = elem & (KDIM - 1);
        const float4 v = ((const float4*)x)[i4];
        ushort4 o;
        o.x = f2bf(v.x); o.y = f2bf(v.y); o.z = f2bf(v.z); o.w = f2bf(v.w);
        *(ushort4*)(xb + ((k >> 3) * 32 + b) * 8 + (k & 7)) = o;
        xT[(size_t)(k + 0) * 32 + b] = v.x;
        xT[(size_t)(k + 1) * 32 + b] = v.y;
        xT[(size_t)(k + 2) * 32 + b] = v.z;
        xT[(size_t)(k + 3) * 32 + b] = v.w;
    }

    double s = 0.0;
#pragma unroll 4
    for (int j = 0; j < 43; ++j) {                     // 262144 * 43 == WCOUNT/4
        const int i4 = tid + j * 262144;
        const float4 v = w4[i4];
        const int row = i4 >> 10;                      // 1024 float4 per W row
        const int kbase = (i4 & 1023) << 2;
        unsigned cc[4];
        const float e[4] = {v.x, v.y, v.z, v.w};
#pragma unroll
        for (int q = 0; q < 4; ++q) {
            const float w = e[q];
            const unsigned wb = __builtin_bit_cast(unsigned, w);
            const float aw = __builtin_fabsf(w);
            s += (double)aw;
            unsigned c;
            if (aw > DHI) {
                c = 1u + (wb >> 31);                   // +1 -> 1, -1 -> 2
            } else if (aw > DLO) {                     // uncertain: log exception
                c = 3u;
                unsigned idx = atomicAdd(&cnt[row], 1u);
                if (idx < 64u)
                    ebuf[(size_t)row * 64 + idx] = make_uint2((unsigned)(kbase + q), wb);
            } else {
                c = 0u;
            }
            cc[q] = c;
        }
        codes[i4] = (unsigned char)(cc[0] | (cc[1] << 2) | (cc[2] << 4) | (cc[3] << 6));
    }
    for (int off = 32; off; off >>= 1) s += __shfl_down(s, off);
    __shared__ double red[4];
    const int lane = threadIdx.x & 63, wv = threadIdx.x >> 6;
    if (lane == 0) red[wv] = s;
    __syncthreads();
    if (threadIdx.x == 0) dpart[blockIdx.x] = red[0] + red[1] + red[2] + red[3];
}

// ---- pass 2: MFMA GEMM from 2-bit codes + exact exception corrections ----
__global__ __launch_bounds__(256, 3) void gemm16_k(const float* __restrict__ W,
                                                   const unsigned char* __restrict__ codes,
                                                   const ushort* __restrict__ xb,
                                                   const float* __restrict__ xT,
                                                   const uint2* __restrict__ ebuf,
                                                   const unsigned* __restrict__ cnt,
                                                   const double* __restrict__ dpart,
                                                   const float* __restrict__ alpha,
                                                   const float* __restrict__ bias,
                                                   float* __restrict__ out) {
    __shared__ float redf[3][32][16];
    __shared__ float corr[16][33];                     // [local out col][batch m], pad 33
    __shared__ double redd[4];
    __shared__ int sbad;
    const int tid = threadIdx.x;
    const int wv = tid >> 6, l = tid & 63;
    const int o0 = blockIdx.x * 16;

    // delta preamble: reduce 1024 partials (fixed order)
    {
        double s = 0.0;
#pragma unroll
        for (int j = 0; j < 4; ++j) s += dpart[tid * 4 + j];
        for (int off = 32; off; off >>= 1) s += __shfl_down(s, off);
        if ((tid & 63) == 0) redd[wv] = s;
    }
    if (tid == 0) sbad = 0;
    __syncthreads();
    const double dsum = redd[0] + redd[1] + redd[2] + redd[3];
    const float dc = delta_fix(0.7 * dsum * (1.0 / (double)WCOUNT));
    if (tid < 16 && cnt[o0 + tid] > 64u) sbad = 1;     // bucket overflow -> raw path
    __syncthreads();
    const bool ok = (dc >= DLO) && (dc <= DHI) && (sbad == 0);

    const int kw0 = wv * 1024;
    const int col = l & 15;
    const int kb  = l >> 4;

    const uint4* xa0 = (const uint4*)xb + ((size_t)(kw0 >> 3) + kb) * 32 + col;
    const uint4* xa1 = xa0 + 16;

    f32x4 acc0, acc1;
#pragma unroll
    for (int i = 0; i < 4; ++i) { acc0[i] = 0.0f; acc1[i] = 0.0f; }

    if (ok) {
        const ushort* cp = (const ushort*)codes + (size_t)(o0 + col) * 512 + (kw0 >> 3) + kb;
        unsigned Cc[PF]; uint4 X0[PF], X1[PF];
#pragma unroll
        for (int p = 0; p < PF; ++p) {
            Cc[p] = cp[p * 4];
            X0[p] = xa0[(size_t)p * 128];
            X1[p] = xa1[(size_t)p * 128];
        }
#pragma unroll
        for (int s = 0; s < 32; ++s) {
            const int bi = s & (PF - 1);
            const unsigned c = Cc[bi];
            uint4 bb;
            bb.x = dec2(c, 0); bb.y = dec2(c, 1);
            bb.z = dec2(c, 2); bb.w = dec2(c, 3);
            const bf16x8 bv = __builtin_bit_cast(bf16x8, bb);
            acc0 = __builtin_amdgcn_mfma_f32_16x16x32_bf16(
                       __builtin_bit_cast(bf16x8, X0[bi]), bv, acc0, 0, 0, 0);
            acc1 = __builtin_amdgcn_mfma_f32_16x16x32_bf16(
                       __builtin_bit_cast(bf16x8, X1[bi]), bv, acc1, 0, 0, 0);
            if (s + PF < 32) {
                Cc[bi] = cp[(s + PF) * 4];
                X0[bi] = xa0[(size_t)(s + PF) * 128];
                X1[bi] = xa1[(size_t)(s + PF) * 128];
            }
        }
    } else {                                           // raw-W fallback (never in practice)
        const float4* wp4 = (const float4*)(W + (size_t)(o0 + col) * KDIM + kw0) + kb * 2;
#pragma unroll 4
        for (int s = 0; s < 32; ++s) {
            float4 w0 = wp4[s * 8], w1 = wp4[s * 8 + 1];
            uint4 bb;
            bb.x = ternpack(w0.x, w0.y, dc);
            bb.y = ternpack(w0.z, w0.w, dc);
            bb.z = ternpack(w1.x, w1.y, dc);
            bb.w = ternpack(w1.z, w1.w, dc);
            const bf16x8 bv = __builtin_bit_cast(bf16x8, bb);
            uint4 a0 = xa0[(size_t)s * 128], a1 = xa1[(size_t)s * 128];
            acc0 = __builtin_amdgcn_mfma_f32_16x16x32_bf16(
                       __builtin_bit_cast(bf16x8, a0), bv, acc0, 0, 0, 0);
            acc1 = __builtin_amdgcn_mfma_f32_16x16x32_bf16(
                       __builtin_bit_cast(bf16x8, a1), bv, acc1, 0, 0, 0);
        }
    }

    // cross-wave reduce staging
    if (wv > 0) {
#pragma unroll
        for (int j = 0; j < 4; ++j) {
            redf[wv - 1][kb * 4 + j][col]      = acc0[j];
            redf[wv - 1][16 + kb * 4 + j][col] = acc1[j];
        }
    }

    // exception corrections: each half-wave covers 2 local rows; one write per (r,m)
    if (ok) {
        const int m = l & 31;
        const int h2 = l >> 5;
#pragma unroll
        for (int rr = 0; rr < 2; ++rr) {
            const int r = wv + 4 * (h2 + 2 * rr);      // covers 0..15 across 4 waves
            const int o = o0 + r;
            const unsigned n = min(cnt[o], 64u);
            float rc = 0.0f;
            for (unsigned e = 0; e < n; ++e) {
                const uint2 u2 = ebuf[(size_t)o * 64 + e];
                const float w = __builtin_bit_cast(float, u2.y);
                if (__builtin_fabsf(w) > dc) {
                    const float xv = xT[(size_t)u2.x * 32 + m];
                    rc += (u2.y >> 31) ? -xv : xv;
                }
            }
            corr[r][m] = rc;
        }
    }
    __syncthreads();

    if (wv == 0) {
        const float a = *alpha;
        const float bn = bias[o0 + col];
#pragma unroll
        for (int j = 0; j < 4; ++j) {
            const int m0 = kb * 4 + j;
            float v0 = acc0[j] + redf[0][m0][col] + redf[1][m0][col] + redf[2][m0][col];
            if (ok) v0 += corr[col][m0];
            out[(size_t)m0 * OUTN + o0 + col] = fmaf(a, v0, bn);
            const int m1 = 16 + kb * 4 + j;
            float v1 = acc1[j] + redf[0][m1][col] + redf[1][m1][col] + redf[2][m1][col];
            if (ok) v1 += corr[col][m1];
            out[(size_t)m1 * OUTN + o0 + col] = fmaf(a, v1, bn);
        }
    }
}

// ---------------- fallback (tiny ws): two-pass, direct out, 32x32x16 ----------------
__global__ __launch_bounds__(256) void abssum_k(const float4* __restrict__ w4,
                                                double* __restrict__ dsum) {
    const int tid = blockIdx.x * 256 + threadIdx.x;
    double s = 0.0;
#pragma unroll 8
    for (int j = 0; j < 43; ++j) {
        float4 v = w4[tid + j * 262144];
        s += (double)(fabsf(v.x) + fabsf(v.y)) + (double)(fabsf(v.z) + fabsf(v.w));
    }
    for (int off = 32; off; off >>= 1) s += __shfl_down(s, off);
    __shared__ double red[4];
    const int lane = threadIdx.x & 63, wv = threadIdx.x >> 6;
    if (lane == 0) red[wv] = s;
    __syncthreads();
    if (threadIdx.x == 0) atomicAdd(dsum, red[0] + red[1] + red[2] + red[3]);
}

__global__ __launch_bounds__(64) void gemm1_k(const float* __restrict__ W,
                                              const float* __restrict__ x,
                                              const double* __restrict__ dsum,
                                              float* __restrict__ dst,
                                              const float* __restrict__ alpha,
                                              const float* __restrict__ bias) {
    const int l = threadIdx.x;
    const int o0 = blockIdx.x * 32;
    const float delta = delta_fix(0.7 * (*dsum) * (1.0 / (double)WCOUNT));
    const int row = l & 31, half = l >> 5;
    const float4* wp = (const float4*)(W + (size_t)(o0 + row) * KDIM + half * 8);
    const float4* xp = (const float4*)(x + (size_t)row * KDIM + half * 8);

    f32x16 acc;
#pragma unroll
    for (int i = 0; i < 16; ++i) acc[i] = 0.0f;

#pragma unroll 8
    for (int s = 0; s < 256; ++s) {
        float4 w0 = wp[s * 4], w1 = wp[s * 4 + 1];
        uint4 bb;
        bb.x = ternpack(w0.x, w0.y, delta);
        bb.y = ternpack(w0.z, w0.w, delta);
        bb.z = ternpack(w1.x, w1.y, delta);
        bb.w = ternpack(w1.z, w1.w, delta);
        float4 v0 = xp[s * 4], v1 = xp[s * 4 + 1];
        struct U { ushort s[8]; } uu;
        uu.s[0] = f2bf(v0.x); uu.s[1] = f2bf(v0.y);
        uu.s[2] = f2bf(v0.z); uu.s[3] = f2bf(v0.w);
        uu.s[4] = f2bf(v1.x); uu.s[5] = f2bf(v1.y);
        uu.s[6] = f2bf(v1.z); uu.s[7] = f2bf(v1.w);
        acc = __builtin_amdgcn_mfma_f32_32x32x16_bf16(
                  __builtin_bit_cast(bf16x8, uu), __builtin_bit_cast(bf16x8, bb),
                  acc, 0, 0, 0);
    }
    const float a = *alpha;
#pragma unroll
    for (int rg = 0; rg < 16; ++rg) {
        const int m = (rg & 3) + 8 * (rg >> 2) + 4 * half;
        const int n = o0 + row;
        dst[(size_t)m * OUTN + n] = fmaf(a, acc[rg], bias[n]);
    }
}

extern "C" void kernel_launch(void* const* d_in, const int* in_sizes, int n_in,
                              void* d_out, int out_size, void* d_ws, size_t ws_size,
                              hipStream_t stream) {
    const float* x     = (const float*)d_in[0];
    const float* W     = (const float*)d_in[1];
    const float* alpha = (const float*)d_in[2];
    const float* bias  = (const float*)d_in[3];
    float* out = (float*)d_out;

    const size_t CNT_OFF = 8192;                 // u32[11008] = 44 KB
    const size_t XB_OFF  = 65536;                // bf16 frags, 256 KB
    const size_t XT_OFF  = 327680;               // f32 xT[4096][32], 512 KB
    const size_t EB_OFF  = 1u << 20;             // uint2[11008][64], 5.5 MB
    const size_t CD_OFF  = 8u << 20;             // 2-bit codes, 11.25 MB
    const size_t TOTAL   = CD_OFF + (size_t)(WCOUNT / 4);

    if (ws_size >= TOTAL) {
        double* dpart = (double*)d_ws;
        unsigned* cnt = (unsigned*)((char*)d_ws + CNT_OFF);
        ushort* xb = (ushort*)((char*)d_ws + XB_OFF);
        float* xT = (float*)((char*)d_ws + XT_OFF);
        uint2* ebuf = (uint2*)((char*)d_ws + EB_OFF);
        unsigned char* codes = (unsigned char*)((char*)d_ws + CD_OFF);

        (void)hipMemsetAsync(cnt, 0, OUTN * sizeof(unsigned), stream);
        prep_k<<<NPB, 256, 0, stream>>>((const float4*)W, x, xb, xT, codes, cnt, ebuf, dpart);
        gemm16_k<<<NT16, 256, 0, stream>>>(W, codes, xb, xT, ebuf, cnt, dpart, alpha, bias, out);
    } else {
        double* dsum = (double*)d_ws;
        (void)hipMemsetAsync(d_ws, 0, 16, stream);
        abssum_k<<<1024, 256, 0, stream>>>((const float4*)W, dsum);
        gemm1_k<<<344, 64, 0, stream>>>(W, x, dsum, out, alpha, bias);
    }
}

// Round 11
// 95.358 us; speedup vs baseline: 1.0651x; 1.0651x over previous
//
#include <hip/hip_runtime.h>
#include <hip/hip_bf16.h>

#define OUTN 11008
#define KDIM 4096
#define BDIM 32
#define NT16 688          // OUTN / 16
#define WCOUNT 45088768   // OUTN * KDIM
#define PF   8            // software-pipeline depth (power of 2)
#define NPB  1024         // prep blocks / partials
#define DLO  0.0069560f   // conservative band around expected delta 6.97585e-3 (+-33 sigma)
#define DHI  0.0069960f

typedef __bf16 bf16x8 __attribute__((ext_vector_type(8)));
typedef float f32x4  __attribute__((ext_vector_type(4)));
typedef float f32x16 __attribute__((ext_vector_type(16)));

__device__ __forceinline__ ushort f2bf(float f) {
    unsigned u = __builtin_bit_cast(unsigned, f);
    u = (u + 0x7FFFu + ((u >> 16) & 1u)) >> 16;
    return (ushort)u;
}

// ternary as f32 bits: sign(w)*1.0f if |w|>d else 0 (raw fallback path)
__device__ __forceinline__ unsigned tern1(float w, float d) {
    unsigned b = __builtin_bit_cast(unsigned, w);
    unsigned s = (b & 0x80000000u) | 0x3F800000u;
    return (__builtin_fabsf(w) > d) ? s : 0u;
}
__device__ __forceinline__ unsigned ternpack(float a, float b, float d) {
    return __builtin_amdgcn_perm(tern1(b, d), tern1(a, d), 0x07060302u);
}

__device__ __forceinline__ float delta_fix(double delta_d) {
    float dc = (float)delta_d;
    if ((double)dc > delta_d)          // largest f32 <= delta_f64
        dc = __builtin_bit_cast(float, __builtin_bit_cast(unsigned, dc) - 1u);
    return dc;
}

// decode crumb pair (elems 2j, 2j+1) of 16-bit code word -> u32 of 2 bf16
// codes: 0 -> 0x0000, 1 -> 0x3F80 (+1), 2 -> 0xBF80 (-1), 3(EXC) -> 0x0000
__device__ __forceinline__ unsigned dec2(unsigned c, int j) {
    unsigned c0 = (c >> (4 * j)) & 3u;
    unsigned c1 = (c >> (4 * j + 2)) & 3u;
    unsigned m = c0 | (c1 << 16);
    unsigned sel = m + (m << 8) + 0x04000400u;
    return __builtin_amdgcn_perm(0x00BF3F00u, 0x00808000u, sel);
}

// ---- pass 1: abssum partials + branchless 2-bit ternary codes + x conv ----
__global__ __launch_bounds__(256) void prep_k(const float4* __restrict__ w4,
                                              const float* __restrict__ x,
                                              ushort* __restrict__ xb,
                                              float* __restrict__ xT,
                                              unsigned char* __restrict__ codes,
                                              double* __restrict__ dpart) {
    const int tid = blockIdx.x * 256 + threadIdx.x;    // grid fixed at NPB blocks

    // x f32 -> bf16 fragment-ordered [K/8][32][8] + f32 transposed copy xT[4096][32]
    if (threadIdx.x < 32) {
        const int i4 = blockIdx.x * 32 + threadIdx.x;  // 0..32767
        const int elem = i4 * 4;
        const int b = elem >> 12;
        const int k = elem & (KDIM - 1);
        const float4 v = ((const float4*)x)[i4];
        ushort4 o;
        o.x = f2bf(v.x); o.y = f2bf(v.y); o.z = f2bf(v.z); o.w = f2bf(v.w);
        *(ushort4*)(xb + ((k >> 3) * 32 + b) * 8 + (k & 7)) = o;
        xT[(size_t)(k + 0) * 32 + b] = v.x;
        xT[(size_t)(k + 1) * 32 + b] = v.y;
        xT[(size_t)(k + 2) * 32 + b] = v.z;
        xT[(size_t)(k + 3) * 32 + b] = v.w;
    }

    double s = 0.0;
#pragma unroll 8
    for (int j = 0; j < 43; ++j) {                     // 262144 * 43 == WCOUNT/4
        const int i4 = tid + j * 262144;
        const float4 v = w4[i4];
        const float a0 = __builtin_fabsf(v.x), a1 = __builtin_fabsf(v.y);
        const float a2 = __builtin_fabsf(v.z), a3 = __builtin_fabsf(v.w);
        s += (double)(a0 + a1) + (double)(a2 + a3);
        const unsigned b0 = __builtin_bit_cast(unsigned, v.x) >> 31;
        const unsigned b1 = __builtin_bit_cast(unsigned, v.y) >> 31;
        const unsigned b2 = __builtin_bit_cast(unsigned, v.z) >> 31;
        const unsigned b3 = __builtin_bit_cast(unsigned, v.w) >> 31;
        // branchless: >DHI -> 1+sign, in (DLO,DHI] -> 3 (exception), else 0
        const unsigned c0 = (a0 > DHI) ? (1u + b0) : ((a0 > DLO) ? 3u : 0u);
        const unsigned c1 = (a1 > DHI) ? (1u + b1) : ((a1 > DLO) ? 3u : 0u);
        const unsigned c2 = (a2 > DHI) ? (1u + b2) : ((a2 > DLO) ? 3u : 0u);
        const unsigned c3 = (a3 > DHI) ? (1u + b3) : ((a3 > DLO) ? 3u : 0u);
        codes[i4] = (unsigned char)(c0 | (c1 << 2) | (c2 << 4) | (c3 << 6));
    }
    for (int off = 32; off; off >>= 1) s += __shfl_down(s, off);
    __shared__ double red[4];
    const int lane = threadIdx.x & 63, wv = threadIdx.x >> 6;
    if (lane == 0) red[wv] = s;
    __syncthreads();
    if (threadIdx.x == 0) dpart[blockIdx.x] = red[0] + red[1] + red[2] + red[3];
}

// ---- pass 2: MFMA GEMM from 2-bit codes + post-loop exception sweep ----
__global__ __launch_bounds__(256, 3) void gemm16_k(const float* __restrict__ W,
                                                   const unsigned char* __restrict__ codes,
                                                   const ushort* __restrict__ xb,
                                                   const float* __restrict__ xT,
                                                   const double* __restrict__ dpart,
                                                   const float* __restrict__ alpha,
                                                   const float* __restrict__ bias,
                                                   float* __restrict__ out) {
    __shared__ float redf[3][32][16];
    __shared__ float corr[16][33];                     // [local W row][batch m], padded
    __shared__ double redd[4];
    const int tid = threadIdx.x;
    const int wv = tid >> 6, l = tid & 63;
    const int o0 = blockIdx.x * 16;

    // zero correction accumulators (visible after the preamble barrier)
    for (int i = tid; i < 16 * 33; i += 256) (&corr[0][0])[i] = 0.0f;

    // delta preamble: reduce 1024 partials (fixed order, identical per block)
    {
        double s = 0.0;
#pragma unroll
        for (int j = 0; j < 4; ++j) s += dpart[tid * 4 + j];
        for (int off = 32; off; off >>= 1) s += __shfl_down(s, off);
        if ((tid & 63) == 0) redd[wv] = s;
    }
    __syncthreads();
    const double dsum = redd[0] + redd[1] + redd[2] + redd[3];
    const float dc = delta_fix(0.7 * dsum * (1.0 / (double)WCOUNT));
    const bool ok = (dc >= DLO) && (dc <= DHI);        // uniform across grid

    const int kw0 = wv * 1024;
    const int col = l & 15;                            // local W row / out col
    const int kb  = l >> 4;

    const uint4* xa0 = (const uint4*)xb + ((size_t)(kw0 >> 3) + kb) * 32 + col;
    const uint4* xa1 = xa0 + 16;

    f32x4 acc0, acc1;
#pragma unroll
    for (int i = 0; i < 4; ++i) { acc0[i] = 0.0f; acc1[i] = 0.0f; }

    if (ok) {
        const ushort* cp = (const ushort*)codes + (size_t)(o0 + col) * 512 + (kw0 >> 3) + kb;
        unsigned Cc[PF]; uint4 X0[PF], X1[PF];
#pragma unroll
        for (int p = 0; p < PF; ++p) {
            Cc[p] = cp[p * 4];
            X0[p] = xa0[(size_t)p * 128];
            X1[p] = xa1[(size_t)p * 128];
        }
#pragma unroll
        for (int s = 0; s < 32; ++s) {
            const int bi = s & (PF - 1);
            const unsigned c = Cc[bi];
            uint4 bb;
            bb.x = dec2(c, 0); bb.y = dec2(c, 1);
            bb.z = dec2(c, 2); bb.w = dec2(c, 3);
            const bf16x8 bv = __builtin_bit_cast(bf16x8, bb);
            acc0 = __builtin_amdgcn_mfma_f32_16x16x32_bf16(
                       __builtin_bit_cast(bf16x8, X0[bi]), bv, acc0, 0, 0, 0);
            acc1 = __builtin_amdgcn_mfma_f32_16x16x32_bf16(
                       __builtin_bit_cast(bf16x8, X1[bi]), bv, acc1, 0, 0, 0);
            if (s + PF < 32) {
                Cc[bi] = cp[(s + PF) * 4];
                X0[bi] = xa0[(size_t)(s + PF) * 128];
                X1[bi] = xa1[(size_t)(s + PF) * 128];
            }
        }
    } else {                                           // raw-W fallback (band miss)
        const float4* wp4 = (const float4*)(W + (size_t)(o0 + col) * KDIM + kw0) + kb * 2;
#pragma unroll 4
        for (int s = 0; s < 32; ++s) {
            float4 w0 = wp4[s * 8], w1 = wp4[s * 8 + 1];
            uint4 bb;
            bb.x = ternpack(w0.x, w0.y, dc);
            bb.y = ternpack(w0.z, w0.w, dc);
            bb.z = ternpack(w1.x, w1.y, dc);
            bb.w = ternpack(w1.z, w1.w, dc);
            const bf16x8 bv = __builtin_bit_cast(bf16x8, bb);
            uint4 a0 = xa0[(size_t)s * 128], a1 = xa1[(size_t)s * 128];
            acc0 = __builtin_amdgcn_mfma_f32_16x16x32_bf16(
                       __builtin_bit_cast(bf16x8, a0), bv, acc0, 0, 0, 0);
            acc1 = __builtin_amdgcn_mfma_f32_16x16x32_bf16(
                       __builtin_bit_cast(bf16x8, a1), bv, acc1, 0, 0, 0);
        }
    }

    // cross-wave reduce staging
    if (wv > 0) {
#pragma unroll
        for (int j = 0; j < 4; ++j) {
            redf[wv - 1][kb * 4 + j][col]      = acc0[j];
            redf[wv - 1][16 + kb * 4 + j][col] = acc1[j];
        }
    }

    // exception sweep: rescan this tile's codes for crumb==3 (rare), exact fix
    if (ok) {
        const int r = tid >> 4;                        // local W row 0..15
        const int w0i = (tid & 15) * 32;               // 32 ushort words per thread
        const ushort* cw = (const ushort*)codes + (size_t)(o0 + r) * 512 + w0i;
        for (int i = 0; i < 32; ++i) {
            const unsigned c = cw[i];
            if (c & (c >> 1) & 0x5555u) {
#pragma unroll
                for (int p = 0; p < 8; ++p) {
                    if (((c >> (2 * p)) & 3u) == 3u) {
                        const int k = (w0i + i) * 8 + p;
                        const float w = W[(size_t)(o0 + r) * KDIM + k];
                        if (__builtin_fabsf(w) > dc) {
                            const float sg =
                                (__builtin_bit_cast(unsigned, w) >> 31) ? -1.0f : 1.0f;
                            for (int m = 0; m < 32; ++m)
                                atomicAdd(&corr[r][m], sg * xT[(size_t)k * 32 + m]);
                        }
                    }
                }
            }
        }
    }
    __syncthreads();

    if (wv == 0) {
        const float a = *alpha;
        const float bn = bias[o0 + col];
#pragma unroll
        for (int j = 0; j < 4; ++j) {
            const int m0 = kb * 4 + j;
            float v0 = acc0[j] + redf[0][m0][col] + redf[1][m0][col] + redf[2][m0][col];
            if (ok) v0 += corr[col][m0];
            out[(size_t)m0 * OUTN + o0 + col] = fmaf(a, v0, bn);
            const int m1 = 16 + kb * 4 + j;
            float v1 = acc1[j] + redf[0][m1][col] + redf[1][m1][col] + redf[2][m1][col];
            if (ok) v1 += corr[col][m1];
            out[(size_t)m1 * OUTN + o0 + col] = fmaf(a, v1, bn);
        }
    }
}

// ---------------- fallback (tiny ws): two-pass, direct out, 32x32x16 ----------------
__global__ __launch_bounds__(256) void abssum_k(const float4* __restrict__ w4,
                                                double* __restrict__ dsum) {
    const int tid = blockIdx.x * 256 + threadIdx.x;
    double s = 0.0;
#pragma unroll 8
    for (int j = 0; j < 43; ++j) {
        float4 v = w4[tid + j * 262144];
        s += (double)(fabsf(v.x) + fabsf(v.y)) + (double)(fabsf(v.z) + fabsf(v.w));
    }
    for (int off = 32; off; off >>= 1) s += __shfl_down(s, off);
    __shared__ double red[4];
    const int lane = threadIdx.x & 63, wv = threadIdx.x >> 6;
    if (lane == 0) red[wv] = s;
    __syncthreads();
    if (threadIdx.x == 0) atomicAdd(dsum, red[0] + red[1] + red[2] + red[3]);
}

__global__ __launch_bounds__(64) void gemm1_k(const float* __restrict__ W,
                                              const float* __restrict__ x,
                                              const double* __restrict__ dsum,
                                              float* __restrict__ dst,
                                              const float* __restrict__ alpha,
                                              const float* __restrict__ bias) {
    const int l = threadIdx.x;
    const int o0 = blockIdx.x * 32;
    const float delta = delta_fix(0.7 * (*dsum) * (1.0 / (double)WCOUNT));
    const int row = l & 31, half = l >> 5;
    const float4* wp = (const float4*)(W + (size_t)(o0 + row) * KDIM + half * 8);
    const float4* xp = (const float4*)(x + (size_t)row * KDIM + half * 8);

    f32x16 acc;
#pragma unroll
    for (int i = 0; i < 16; ++i) acc[i] = 0.0f;

#pragma unroll 8
    for (int s = 0; s < 256; ++s) {
        float4 w0 = wp[s * 4], w1 = wp[s * 4 + 1];
        uint4 bb;
        bb.x = ternpack(w0.x, w0.y, delta);
        bb.y = ternpack(w0.z, w0.w, delta);
        bb.z = ternpack(w1.x, w1.y, delta);
        bb.w = ternpack(w1.z, w1.w, delta);
        float4 v0 = xp[s * 4], v1 = xp[s * 4 + 1];
        struct U { ushort s[8]; } uu;
        uu.s[0] = f2bf(v0.x); uu.s[1] = f2bf(v0.y);
        uu.s[2] = f2bf(v0.z); uu.s[3] = f2bf(v0.w);
        uu.s[4] = f2bf(v1.x); uu.s[5] = f2bf(v1.y);
        uu.s[6] = f2bf(v1.z); uu.s[7] = f2bf(v1.w);
        acc = __builtin_amdgcn_mfma_f32_32x32x16_bf16(
                  __builtin_bit_cast(bf16x8, uu), __builtin_bit_cast(bf16x8, bb),
                  acc, 0, 0, 0);
    }
    const float a = *alpha;
#pragma unroll
    for (int rg = 0; rg < 16; ++rg) {
        const int m = (rg & 3) + 8 * (rg >> 2) + 4 * half;
        const int n = o0 + row;
        dst[(size_t)m * OUTN + n] = fmaf(a, acc[rg], bias[n]);
    }
}

extern "C" void kernel_launch(void* const* d_in, const int* in_sizes, int n_in,
                              void* d_out, int out_size, void* d_ws, size_t ws_size,
                              hipStream_t stream) {
    const float* x     = (const float*)d_in[0];
    const float* W     = (const float*)d_in[1];
    const float* alpha = (const float*)d_in[2];
    const float* bias  = (const float*)d_in[3];
    float* out = (float*)d_out;

    const size_t XB_OFF = 65536;                 // bf16 frags, 256 KB
    const size_t XT_OFF = 393216;                // f32 xT[4096][32], 512 KB
    const size_t CD_OFF = 1u << 20;              // 2-bit codes, 11.25 MB
    const size_t TOTAL  = CD_OFF + (size_t)(WCOUNT / 4);

    if (ws_size >= TOTAL) {
        double* dpart = (double*)d_ws;           // 8 KB partials @ 0
        ushort* xb = (ushort*)((char*)d_ws + XB_OFF);
        float* xT = (float*)((char*)d_ws + XT_OFF);
        unsigned char* codes = (unsigned char*)((char*)d_ws + CD_OFF);

        prep_k<<<NPB, 256, 0, stream>>>((const float4*)W, x, xb, xT, codes, dpart);
        gemm16_k<<<NT16, 256, 0, stream>>>(W, codes, xb, xT, dpart, alpha, bias, out);
    } else {
        double* dsum = (double*)d_ws;
        (void)hipMemsetAsync(d_ws, 0, 16, stream);
        abssum_k<<<1024, 256, 0, stream>>>((const float4*)W, dsum);
        gemm1_k<<<344, 64, 0, stream>>>(W, x, dsum, out, alpha, bias);
    }
}

// Round 12
// 66.860 us; speedup vs baseline: 1.5191x; 1.4262x over previous
//
#include <hip/hip_runtime.h>
#include <hip/hip_bf16.h>

#define OUTN 11008
#define KDIM 4096
#define BDIM 32
#define NT16 688          // OUTN / 16
#define WCOUNT 45088768   // OUTN * KDIM
#define PF   8            // X software-pipeline depth
#define NPB  1024         // prep blocks / partials
#define DLO  0.0069560f   // conservative band around expected delta 6.97585e-3 (+-33 sigma)
#define DHI  0.0069960f

typedef __bf16 bf16x8 __attribute__((ext_vector_type(8)));
typedef float f32x4  __attribute__((ext_vector_type(4)));
typedef float f32x16 __attribute__((ext_vector_type(16)));

__device__ __forceinline__ ushort f2bf(float f) {
    unsigned u = __builtin_bit_cast(unsigned, f);
    u = (u + 0x7FFFu + ((u >> 16) & 1u)) >> 16;
    return (ushort)u;
}

// ternary as f32 bits: sign(w)*1.0f if |w|>d else 0 (raw fallback path)
__device__ __forceinline__ unsigned tern1(float w, float d) {
    unsigned b = __builtin_bit_cast(unsigned, w);
    unsigned s = (b & 0x80000000u) | 0x3F800000u;
    return (__builtin_fabsf(w) > d) ? s : 0u;
}
__device__ __forceinline__ unsigned ternpack(float a, float b, float d) {
    return __builtin_amdgcn_perm(tern1(b, d), tern1(a, d), 0x07060302u);
}

__device__ __forceinline__ float delta_fix(double delta_d) {
    float dc = (float)delta_d;
    if ((double)dc > delta_d)          // largest f32 <= delta_f64
        dc = __builtin_bit_cast(float, __builtin_bit_cast(unsigned, dc) - 1u);
    return dc;
}

// decode crumb pair (elems 2j, 2j+1) of 16-bit code word -> u32 of 2 bf16
// codes: 0 -> 0x0000, 1 -> 0x3F80 (+1), 2 -> 0xBF80 (-1), 3(EXC) -> 0x0000
__device__ __forceinline__ unsigned dec2(unsigned c, int j) {
    unsigned c0 = (c >> (4 * j)) & 3u;
    unsigned c1 = (c >> (4 * j + 2)) & 3u;
    unsigned m = c0 | (c1 << 16);
    unsigned sel = m + (m << 8) + 0x04000400u;
    return __builtin_amdgcn_perm(0x00BF3F00u, 0x00808000u, sel);
}

// ---- pass 1: abssum partials + branchless 2-bit ternary codes + x conv ----
__global__ __launch_bounds__(256) void prep_k(const float4* __restrict__ w4,
                                              const float* __restrict__ x,
                                              ushort* __restrict__ xb,
                                              float* __restrict__ xT,
                                              unsigned char* __restrict__ codes,
                                              double* __restrict__ dpart) {
    const int tid = blockIdx.x * 256 + threadIdx.x;    // grid fixed at NPB blocks

    // x f32 -> bf16 fragment-ordered [K/8][32][8] + f32 transposed copy xT[4096][32]
    if (threadIdx.x < 32) {
        const int i4 = blockIdx.x * 32 + threadIdx.x;  // 0..32767
        const int elem = i4 * 4;
        const int b = elem >> 12;
        const int k = elem & (KDIM - 1);
        const float4 v = ((const float4*)x)[i4];
        ushort4 o;
        o.x = f2bf(v.x); o.y = f2bf(v.y); o.z = f2bf(v.z); o.w = f2bf(v.w);
        *(ushort4*)(xb + ((k >> 3) * 32 + b) * 8 + (k & 7)) = o;
        xT[(size_t)(k + 0) * 32 + b] = v.x;
        xT[(size_t)(k + 1) * 32 + b] = v.y;
        xT[(size_t)(k + 2) * 32 + b] = v.z;
        xT[(size_t)(k + 3) * 32 + b] = v.w;
    }

    double s = 0.0;
#pragma unroll 8
    for (int j = 0; j < 43; ++j) {                     // 262144 * 43 == WCOUNT/4
        const int i4 = tid + j * 262144;
        const float4 v = w4[i4];
        const float a0 = __builtin_fabsf(v.x), a1 = __builtin_fabsf(v.y);
        const float a2 = __builtin_fabsf(v.z), a3 = __builtin_fabsf(v.w);
        s += (double)(a0 + a1) + (double)(a2 + a3);
        const unsigned b0 = __builtin_bit_cast(unsigned, v.x) >> 31;
        const unsigned b1 = __builtin_bit_cast(unsigned, v.y) >> 31;
        const unsigned b2 = __builtin_bit_cast(unsigned, v.z) >> 31;
        const unsigned b3 = __builtin_bit_cast(unsigned, v.w) >> 31;
        // branchless: >DHI -> 1+sign, in (DLO,DHI] -> 3 (exception), else 0
        const unsigned c0 = (a0 > DHI) ? (1u + b0) : ((a0 > DLO) ? 3u : 0u);
        const unsigned c1 = (a1 > DHI) ? (1u + b1) : ((a1 > DLO) ? 3u : 0u);
        const unsigned c2 = (a2 > DHI) ? (1u + b2) : ((a2 > DLO) ? 3u : 0u);
        const unsigned c3 = (a3 > DHI) ? (1u + b3) : ((a3 > DLO) ? 3u : 0u);
        codes[i4] = (unsigned char)(c0 | (c1 << 2) | (c2 << 4) | (c3 << 6));
    }
    for (int off = 32; off; off >>= 1) s += __shfl_down(s, off);
    __shared__ double red[4];
    const int lane = threadIdx.x & 63, wv = threadIdx.x >> 6;
    if (lane == 0) red[wv] = s;
    __syncthreads();
    if (threadIdx.x == 0) dpart[blockIdx.x] = red[0] + red[1] + red[2] + red[3];
}

// ---- pass 2: MFMA GEMM from 2-bit codes (coalesced) + coalesced exception sweep ----
__global__ __launch_bounds__(256, 3) void gemm16_k(const float* __restrict__ W,
                                                   const unsigned char* __restrict__ codes,
                                                   const ushort* __restrict__ xb,
                                                   const float* __restrict__ xT,
                                                   const double* __restrict__ dpart,
                                                   const float* __restrict__ alpha,
                                                   const float* __restrict__ bias,
                                                   float* __restrict__ out) {
    __shared__ float redf[3][32][16];
    __shared__ float corr[16][33];                     // [local W row][batch m], padded
    __shared__ double redd[4];
    const int tid = threadIdx.x;
    const int wv = tid >> 6, l = tid & 63;
    const int o0 = blockIdx.x * 16;

    // zero correction accumulators (visible after the preamble barrier)
    for (int i = tid; i < 16 * 33; i += 256) (&corr[0][0])[i] = 0.0f;

    // delta preamble: reduce 1024 partials (fixed order, identical per block)
    {
        double s = 0.0;
#pragma unroll
        for (int j = 0; j < 4; ++j) s += dpart[tid * 4 + j];
        for (int off = 32; off; off >>= 1) s += __shfl_down(s, off);
        if ((tid & 63) == 0) redd[wv] = s;
    }
    __syncthreads();
    const double dsum = redd[0] + redd[1] + redd[2] + redd[3];
    const float dc = delta_fix(0.7 * dsum * (1.0 / (double)WCOUNT));
    const bool ok = (dc >= DLO) && (dc <= DHI);        // uniform across grid

    const int kw0 = wv * 1024;
    const int col = l & 15;                            // local W row / out col
    const int kb  = l >> 4;

    const uint4* xa0 = (const uint4*)xb + ((size_t)(kw0 >> 3) + kb) * 32 + col;
    const uint4* xa1 = xa0 + 16;

    f32x4 acc0, acc1;
#pragma unroll
    for (int i = 0; i < 4; ++i) { acc0[i] = 0.0f; acc1[i] = 0.0f; }

    if (ok) {
        // codes for this lane's row, this wave's K-chunk: 16 uint4 (2 steps each).
        // 4 lanes (same col, different kb) broadcast the same address; per-lane
        // v_perm selector extracts the (s, kb) word.
        const uint4* cq = (const uint4*)(codes + (size_t)(o0 + col) * 1024) + wv * 16;
        const unsigned selc = 0x0C0C0100u + (unsigned)kb * 0x0202u;
        uint4 CQ[4]; uint4 X0[PF], X1[PF];
#pragma unroll
        for (int p = 0; p < 4; ++p) CQ[p] = cq[p];
#pragma unroll
        for (int p = 0; p < PF; ++p) {
            X0[p] = xa0[(size_t)p * 128];
            X1[p] = xa1[(size_t)p * 128];
        }
#pragma unroll
        for (int s = 0; s < 32; ++s) {
            const int bi = s & (PF - 1);
            const int q = (s >> 1) & 3;
            const unsigned c16 = (s & 1)
                ? __builtin_amdgcn_perm(CQ[q].w, CQ[q].z, selc)
                : __builtin_amdgcn_perm(CQ[q].y, CQ[q].x, selc);
            uint4 bb;
            bb.x = dec2(c16, 0); bb.y = dec2(c16, 1);
            bb.z = dec2(c16, 2); bb.w = dec2(c16, 3);
            const bf16x8 bv = __builtin_bit_cast(bf16x8, bb);
            acc0 = __builtin_amdgcn_mfma_f32_16x16x32_bf16(
                       __builtin_bit_cast(bf16x8, X0[bi]), bv, acc0, 0, 0, 0);
            acc1 = __builtin_amdgcn_mfma_f32_16x16x32_bf16(
                       __builtin_bit_cast(bf16x8, X1[bi]), bv, acc1, 0, 0, 0);
            if (s + PF < 32) {
                X0[bi] = xa0[(size_t)(s + PF) * 128];
                X1[bi] = xa1[(size_t)(s + PF) * 128];
            }
            if ((s & 1) && ((s >> 1) + 4) < 16) CQ[q] = cq[(s >> 1) + 4];
        }
    } else {                                           // raw-W fallback (band miss)
        const float4* wp4 = (const float4*)(W + (size_t)(o0 + col) * KDIM + kw0) + kb * 2;
#pragma unroll 4
        for (int s = 0; s < 32; ++s) {
            float4 w0 = wp4[s * 8], w1 = wp4[s * 8 + 1];
            uint4 bb;
            bb.x = ternpack(w0.x, w0.y, dc);
            bb.y = ternpack(w0.z, w0.w, dc);
            bb.z = ternpack(w1.x, w1.y, dc);
            bb.w = ternpack(w1.z, w1.w, dc);
            const bf16x8 bv = __builtin_bit_cast(bf16x8, bb);
            uint4 a0 = xa0[(size_t)s * 128], a1 = xa1[(size_t)s * 128];
            acc0 = __builtin_amdgcn_mfma_f32_16x16x32_bf16(
                       __builtin_bit_cast(bf16x8, a0), bv, acc0, 0, 0, 0);
            acc1 = __builtin_amdgcn_mfma_f32_16x16x32_bf16(
                       __builtin_bit_cast(bf16x8, a1), bv, acc1, 0, 0, 0);
        }
    }

    // cross-wave reduce staging
    if (wv > 0) {
#pragma unroll
        for (int j = 0; j < 4; ++j) {
            redf[wv - 1][kb * 4 + j][col]      = acc0[j];
            redf[wv - 1][16 + kb * 4 + j][col] = acc1[j];
        }
    }

    // exception sweep: coalesced uint4 scan of this block's 16 KB code chunk
    if (ok) {
        const uint4* cb = (const uint4*)(codes + (size_t)o0 * 1024);
#pragma unroll
        for (int it = 0; it < 4; ++it) {
            const uint4 u = cb[it * 256 + tid];
            const unsigned cw[4] = {u.x, u.y, u.z, u.w};
#pragma unroll
            for (int d = 0; d < 4; ++d) {
                unsigned hit = cw[d] & (cw[d] >> 1) & 0x55555555u;
                while (hit) {
                    const int p = __builtin_ctz(hit);
                    hit &= hit - 1;
                    const int q = p >> 1;              // elem 0..15 within dword
                    const int ofs = it * 4096 + tid * 16 + d * 4;  // dword byte offset
                    const int row = ofs >> 10;
                    const int k = ((ofs & 1023) << 2) + q;
                    const float w = W[(size_t)(o0 + row) * KDIM + k];
                    if (__builtin_fabsf(w) > dc) {
                        const float sg =
                            (__builtin_bit_cast(unsigned, w) >> 31) ? -1.0f : 1.0f;
                        for (int m = 0; m < 32; ++m)
                            atomicAdd(&corr[row][m], sg * xT[(size_t)k * 32 + m]);
                    }
                }
            }
        }
    }
    __syncthreads();

    if (wv == 0) {
        const float a = *alpha;
        const float bn = bias[o0 + col];
#pragma unroll
        for (int j = 0; j < 4; ++j) {
            const int m0 = kb * 4 + j;
            float v0 = acc0[j] + redf[0][m0][col] + redf[1][m0][col] + redf[2][m0][col];
            if (ok) v0 += corr[col][m0];
            out[(size_t)m0 * OUTN + o0 + col] = fmaf(a, v0, bn);
            const int m1 = 16 + kb * 4 + j;
            float v1 = acc1[j] + redf[0][m1][col] + redf[1][m1][col] + redf[2][m1][col];
            if (ok) v1 += corr[col][m1];
            out[(size_t)m1 * OUTN + o0 + col] = fmaf(a, v1, bn);
        }
    }
}

// ---------------- fallback (tiny ws): two-pass, direct out, 32x32x16 ----------------
__global__ __launch_bounds__(256) void abssum_k(const float4* __restrict__ w4,
                                                double* __restrict__ dsum) {
    const int tid = blockIdx.x * 256 + threadIdx.x;
    double s = 0.0;
#pragma unroll 8
    for (int j = 0; j < 43; ++j) {
        float4 v = w4[tid + j * 262144];
        s += (double)(fabsf(v.x) + fabsf(v.y)) + (double)(fabsf(v.z) + fabsf(v.w));
    }
    for (int off = 32; off; off >>= 1) s += __shfl_down(s, off);
    __shared__ double red[4];
    const int lane = threadIdx.x & 63, wv = threadIdx.x >> 6;
    if (lane == 0) red[wv] = s;
    __syncthreads();
    if (threadIdx.x == 0) atomicAdd(dsum, red[0] + red[1] + red[2] + red[3]);
}

__global__ __launch_bounds__(64) void gemm1_k(const float* __restrict__ W,
                                              const float* __restrict__ x,
                                              const double* __restrict__ dsum,
                                              float* __restrict__ dst,
                                              const float* __restrict__ alpha,
                                              const float* __restrict__ bias) {
    const int l = threadIdx.x;
    const int o0 = blockIdx.x * 32;
    const float delta = delta_fix(0.7 * (*dsum) * (1.0 / (double)WCOUNT));
    const int row = l & 31, half = l >> 5;
    const float4* wp = (const float4*)(W + (size_t)(o0 + row) * KDIM + half * 8);
    const float4* xp = (const float4*)(x + (size_t)row * KDIM + half * 8);

    f32x16 acc;
#pragma unroll
    for (int i = 0; i < 16; ++i) acc[i] = 0.0f;

#pragma unroll 8
    for (int s = 0; s < 256; ++s) {
        float4 w0 = wp[s * 4], w1 = wp[s * 4 + 1];
        uint4 bb;
        bb.x = ternpack(w0.x, w0.y, delta);
        bb.y = ternpack(w0.z, w0.w, delta);
        bb.z = ternpack(w1.x, w1.y, delta);
        bb.w = ternpack(w1.z, w1.w, delta);
        float4 v0 = xp[s * 4], v1 = xp[s * 4 + 1];
        struct U { ushort s[8]; } uu;
        uu.s[0] = f2bf(v0.x); uu.s[1] = f2bf(v0.y);
        uu.s[2] = f2bf(v0.z); uu.s[3] = f2bf(v0.w);
        uu.s[4] = f2bf(v1.x); uu.s[5] = f2bf(v1.y);
        uu.s[6] = f2bf(v1.z); uu.s[7] = f2bf(v1.w);
        acc = __builtin_amdgcn_mfma_f32_32x32x16_bf16(
                  __builtin_bit_cast(bf16x8, uu), __builtin_bit_cast(bf16x8, bb),
                  acc, 0, 0, 0);
    }
    const float a = *alpha;
#pragma unroll
    for (int rg = 0; rg < 16; ++rg) {
        const int m = (rg & 3) + 8 * (rg >> 2) + 4 * half;
        const int n = o0 + row;
        dst[(size_t)m * OUTN + n] = fmaf(a, acc[rg], bias[n]);
    }
}

extern "C" void kernel_launch(void* const* d_in, const int* in_sizes, int n_in,
                              void* d_out, int out_size, void* d_ws, size_t ws_size,
                              hipStream_t stream) {
    const float* x     = (const float*)d_in[0];
    const float* W     = (const float*)d_in[1];
    const float* alpha = (const float*)d_in[2];
    const float* bias  = (const float*)d_in[3];
    float* out = (float*)d_out;

    const size_t XB_OFF = 65536;                 // bf16 frags, 256 KB
    const size_t XT_OFF = 393216;                // f32 xT[4096][32], 512 KB
    const size_t CD_OFF = 1u << 20;              // 2-bit codes, 11.25 MB
    const size_t TOTAL  = CD_OFF + (size_t)(WCOUNT / 4);

    if (ws_size >= TOTAL) {
        double* dpart = (double*)d_ws;           // 8 KB partials @ 0
        ushort* xb = (ushort*)((char*)d_ws + XB_OFF);
        float* xT = (float*)((char*)d_ws + XT_OFF);
        unsigned char* codes = (unsigned char*)((char*)d_ws + CD_OFF);

        prep_k<<<NPB, 256, 0, stream>>>((const float4*)W, x, xb, xT, codes, dpart);
        gemm16_k<<<NT16, 256, 0, stream>>>(W, codes, xb, xT, dpart, alpha, bias, out);
    } else {
        double* dsum = (double*)d_ws;
        (void)hipMemsetAsync(d_ws, 0, 16, stream);
        abssum_k<<<1024, 256, 0, stream>>>((const float4*)W, dsum);
        gemm1_k<<<344, 64, 0, stream>>>(W, x, dsum, out, alpha, bias);
    }
}

// Round 13
// 64.876 us; speedup vs baseline: 1.5656x; 1.0306x over previous
//
#include <hip/hip_runtime.h>
#include <hip/hip_bf16.h>

#define OUTN 11008
#define KDIM 4096
#define BDIM 32
#define NT   344          // OUTN / 32
#define WCOUNT 45088768   // OUTN * KDIM
#define PF   8            // X software-pipeline depth
#define NPB  1024         // prep blocks / partials
#define DLO  0.0069560f   // conservative band around expected delta 6.97585e-3 (+-33 sigma)
#define DHI  0.0069960f

typedef __bf16 bf16x8 __attribute__((ext_vector_type(8)));
typedef float f32x16 __attribute__((ext_vector_type(16)));

__device__ __forceinline__ ushort f2bf(float f) {
    unsigned u = __builtin_bit_cast(unsigned, f);
    u = (u + 0x7FFFu + ((u >> 16) & 1u)) >> 16;
    return (ushort)u;
}

// ternary as f32 bits: sign(w)*1.0f if |w|>d else 0 (raw fallback path)
__device__ __forceinline__ unsigned tern1(float w, float d) {
    unsigned b = __builtin_bit_cast(unsigned, w);
    unsigned s = (b & 0x80000000u) | 0x3F800000u;
    return (__builtin_fabsf(w) > d) ? s : 0u;
}
__device__ __forceinline__ unsigned ternpack(float a, float b, float d) {
    return __builtin_amdgcn_perm(tern1(b, d), tern1(a, d), 0x07060302u);
}

__device__ __forceinline__ float delta_fix(double delta_d) {
    float dc = (float)delta_d;
    if ((double)dc > delta_d)          // largest f32 <= delta_f64
        dc = __builtin_bit_cast(float, __builtin_bit_cast(unsigned, dc) - 1u);
    return dc;
}

// decode crumb pair (elems 2j, 2j+1) of 16-bit code word -> u32 of 2 bf16
// codes: 0 -> 0x0000, 1 -> 0x3F80 (+1), 2 -> 0xBF80 (-1), 3(EXC) -> 0x0000
__device__ __forceinline__ unsigned dec2(unsigned c, int j) {
    unsigned c0 = (c >> (4 * j)) & 3u;
    unsigned c1 = (c >> (4 * j + 2)) & 3u;
    unsigned m = c0 | (c1 << 16);
    unsigned sel = m + (m << 8) + 0x04000400u;
    return __builtin_amdgcn_perm(0x00BF3F00u, 0x00808000u, sel);
}

__device__ __forceinline__ unsigned dwof(const uint4& u, int d) {
    return d == 0 ? u.x : d == 1 ? u.y : d == 2 ? u.z : u.w;   // compile-time d
}

// ---- pass 1: abssum partials + branchless 2-bit ternary codes + x conv ----
__global__ __launch_bounds__(256) void prep_k(const float4* __restrict__ w4,
                                              const float* __restrict__ x,
                                              ushort* __restrict__ xb,
                                              float* __restrict__ xT,
                                              unsigned char* __restrict__ codes,
                                              double* __restrict__ dpart) {
    const int tid = blockIdx.x * 256 + threadIdx.x;    // grid fixed at NPB blocks

    // x f32 -> bf16 fragment-ordered [K/8][32][8] + f32 transposed copy xT[4096][32]
    if (threadIdx.x < 32) {
        const int i4 = blockIdx.x * 32 + threadIdx.x;  // 0..32767
        const int elem = i4 * 4;
        const int b = elem >> 12;
        const int k = elem & (KDIM - 1);
        const float4 v = ((const float4*)x)[i4];
        ushort4 o;
        o.x = f2bf(v.x); o.y = f2bf(v.y); o.z = f2bf(v.z); o.w = f2bf(v.w);
        *(ushort4*)(xb + ((k >> 3) * 32 + b) * 8 + (k & 7)) = o;
        xT[(size_t)(k + 0) * 32 + b] = v.x;
        xT[(size_t)(k + 1) * 32 + b] = v.y;
        xT[(size_t)(k + 2) * 32 + b] = v.z;
        xT[(size_t)(k + 3) * 32 + b] = v.w;
    }

    double s = 0.0;
#pragma unroll 8
    for (int j = 0; j < 43; ++j) {                     // 262144 * 43 == WCOUNT/4
        const int i4 = tid + j * 262144;
        const float4 v = w4[i4];
        const float a0 = __builtin_fabsf(v.x), a1 = __builtin_fabsf(v.y);
        const float a2 = __builtin_fabsf(v.z), a3 = __builtin_fabsf(v.w);
        s += (double)(a0 + a1) + (double)(a2 + a3);
        const unsigned b0 = __builtin_bit_cast(unsigned, v.x) >> 31;
        const unsigned b1 = __builtin_bit_cast(unsigned, v.y) >> 31;
        const unsigned b2 = __builtin_bit_cast(unsigned, v.z) >> 31;
        const unsigned b3 = __builtin_bit_cast(unsigned, v.w) >> 31;
        const unsigned c0 = (a0 > DHI) ? (1u + b0) : ((a0 > DLO) ? 3u : 0u);
        const unsigned c1 = (a1 > DHI) ? (1u + b1) : ((a1 > DLO) ? 3u : 0u);
        const unsigned c2 = (a2 > DHI) ? (1u + b2) : ((a2 > DLO) ? 3u : 0u);
        const unsigned c3 = (a3 > DHI) ? (1u + b3) : ((a3 > DLO) ? 3u : 0u);
        codes[i4] = (unsigned char)(c0 | (c1 << 2) | (c2 << 4) | (c3 << 6));
    }
    for (int off = 32; off; off >>= 1) s += __shfl_down(s, off);
    __shared__ double red[4];
    const int lane = threadIdx.x & 63, wv = threadIdx.x >> 6;
    if (lane == 0) red[wv] = s;
    __syncthreads();
    if (threadIdx.x == 0) dpart[blockIdx.x] = red[0] + red[1] + red[2] + red[3];
}

// ---- pass 2: 32x32x16 MFMA from 2-bit codes; 344 tiles x 4 K-quarters ----
// block = 256 thr (4 waves); wave = 256-wide K slice, 16 MFMA steps of K=16.
// One A-frag load (1 KB/wave-step) feeds 32 output cols -> halves xb L2 traffic.
__global__ __launch_bounds__(256, 4) void gemm32_k(const float* __restrict__ W,
                                                   const unsigned char* __restrict__ codes,
                                                   const ushort* __restrict__ xb,
                                                   const float* __restrict__ xT,
                                                   const double* __restrict__ dpart,
                                                   float* __restrict__ part) {
    __shared__ float redf[3][32][32];
    __shared__ float corr[32][33];
    __shared__ double redd[4];
    const int tid = threadIdx.x;
    const int wv = tid >> 6, l = tid & 63;
    const int tile = blockIdx.x % NT;
    const int ksid = blockIdx.x / NT;                  // 0..3
    const int o0 = tile * 32;

    for (int i = tid; i < 32 * 33; i += 256) (&corr[0][0])[i] = 0.0f;

    // delta preamble: reduce 1024 partials (fixed order, identical per block)
    {
        double s = 0.0;
#pragma unroll
        for (int j = 0; j < 4; ++j) s += dpart[tid * 4 + j];
        for (int off = 32; off; off >>= 1) s += __shfl_down(s, off);
        if ((tid & 63) == 0) redd[wv] = s;
    }
    __syncthreads();
    const double dsum = redd[0] + redd[1] + redd[2] + redd[3];
    const float dc = delta_fix(0.7 * dsum * (1.0 / (double)WCOUNT));
    const bool ok = (dc >= DLO) && (dc <= DHI);        // uniform across grid

    const int row = l & 31, half = l >> 5;             // row = W row = out col
    const int kw0 = ksid * 1024 + wv * 256;            // this wave's K slice

    const uint4* xa = (const uint4*)xb + ((size_t)(kw0 >> 3) + half) * 32 + row;

    f32x16 acc;
#pragma unroll
    for (int i = 0; i < 16; ++i) acc[i] = 0.0f;

    if (ok) {
        // 64 B of codes per (row, wave-slice): 4 uint4; lanes l and l+32 share addr.
        const uint4* cq = (const uint4*)(codes + (size_t)(o0 + row) * 1024 + (kw0 >> 2));
        uint4 CQa[4];
#pragma unroll
        for (int p = 0; p < 4; ++p) CQa[p] = cq[p];
        const unsigned selc = 0x0C0C0100u + (unsigned)half * 0x0202u;  // ushort 'half' of a dword
        uint4 XA[PF];
#pragma unroll
        for (int p = 0; p < PF; ++p) XA[p] = xa[(size_t)p * 64];
#pragma unroll
        for (int s = 0; s < 16; ++s) {                 // 16 steps of K=16
            const unsigned dw = dwof(CQa[s >> 2], s & 3);      // static after unroll
            const unsigned c16 = __builtin_amdgcn_perm(0u, dw, selc);
            uint4 bb;
            bb.x = dec2(c16, 0); bb.y = dec2(c16, 1);
            bb.z = dec2(c16, 2); bb.w = dec2(c16, 3);
            acc = __builtin_amdgcn_mfma_f32_32x32x16_bf16(
                      __builtin_bit_cast(bf16x8, XA[s & (PF - 1)]),
                      __builtin_bit_cast(bf16x8, bb), acc, 0, 0, 0);
            if (s + PF < 16) XA[s & (PF - 1)] = xa[(size_t)(s + PF) * 64];
        }
    } else {                                           // raw-W fallback (band miss)
        const float4* wp = (const float4*)(W + (size_t)(o0 + row) * KDIM + kw0 + half * 8);
#pragma unroll 4
        for (int s = 0; s < 16; ++s) {
            float4 w0 = wp[s * 4], w1 = wp[s * 4 + 1];
            uint4 bb;
            bb.x = ternpack(w0.x, w0.y, dc);
            bb.y = ternpack(w0.z, w0.w, dc);
            bb.z = ternpack(w1.x, w1.y, dc);
            bb.w = ternpack(w1.z, w1.w, dc);
            uint4 a4 = xa[(size_t)s * 64];
            acc = __builtin_amdgcn_mfma_f32_32x32x16_bf16(
                      __builtin_bit_cast(bf16x8, a4), __builtin_bit_cast(bf16x8, bb),
                      acc, 0, 0, 0);
        }
    }

    // cross-wave reduce staging (C/D: col=lane&31, m=(reg&3)+8*(reg>>2)+4*(lane>>5))
    if (wv > 0) {
#pragma unroll
        for (int rg = 0; rg < 16; ++rg) {
            const int m = (rg & 3) + 8 * (rg >> 2) + 4 * half;
            redf[wv - 1][m][row] = acc[rg];
        }
    }

    // exception sweep: this block's 8 KB code slice (32 rows x 256 B), coalesced
    if (ok) {
#pragma unroll
        for (int it = 0; it < 2; ++it) {
            const int idx = it * 256 + tid;            // 0..511
            const int r = idx >> 4;                    // local row 0..31
            const int u4 = idx & 15;                   // uint4 within 256 B slice
            const uint4 u = *(const uint4*)(codes + (size_t)(o0 + r) * 1024 +
                                            ksid * 256 + u4 * 16);
            const unsigned cw[4] = {u.x, u.y, u.z, u.w};
#pragma unroll
            for (int d = 0; d < 4; ++d) {
                unsigned hit = cw[d] & (cw[d] >> 1) & 0x55555555u;
                while (hit) {
                    const int p = __builtin_ctz(hit);
                    hit &= hit - 1;
                    const int k = ksid * 1024 + u4 * 64 + d * 16 + (p >> 1);
                    const float w = W[(size_t)(o0 + r) * KDIM + k];
                    if (__builtin_fabsf(w) > dc) {
                        const float sg =
                            (__builtin_bit_cast(unsigned, w) >> 31) ? -1.0f : 1.0f;
                        for (int m = 0; m < 32; ++m)
                            atomicAdd(&corr[r][m], sg * xT[(size_t)k * 32 + m]);
                    }
                }
            }
        }
    }
    __syncthreads();

    if (wv == 0) {
        float* po = part + (size_t)ksid * (BDIM * OUTN);
#pragma unroll
        for (int rg = 0; rg < 16; ++rg) {
            const int m = (rg & 3) + 8 * (rg >> 2) + 4 * half;
            float v = acc[rg] + redf[0][m][row] + redf[1][m][row] + redf[2][m][row]
                    + corr[row][m];
            po[(size_t)m * OUTN + o0 + row] = v;
        }
    }
}

// ---- pass 3: combine 4 K-quarter partials + alpha + bias ----
__global__ __launch_bounds__(256) void combine_k(const float4* __restrict__ part,
                                                 const float* __restrict__ alpha,
                                                 const float4* __restrict__ bias4,
                                                 float4* __restrict__ out4) {
    const int i = blockIdx.x * 256 + threadIdx.x;      // exactly 88064
    const float a = *alpha;
    float4 s = part[i];
#pragma unroll
    for (int k = 1; k < 4; ++k) {
        float4 p = part[i + (size_t)k * (BDIM * OUTN / 4)];
        s.x += p.x; s.y += p.y; s.z += p.z; s.w += p.w;
    }
    const float4 b = bias4[i % (OUTN / 4)];
    float4 o;
    o.x = fmaf(a, s.x, b.x); o.y = fmaf(a, s.y, b.y);
    o.z = fmaf(a, s.z, b.z); o.w = fmaf(a, s.w, b.w);
    out4[i] = o;
}

// ---------------- fallback (tiny ws): two-pass, direct out, 32x32x16 ----------------
__global__ __launch_bounds__(256) void abssum_k(const float4* __restrict__ w4,
                                                double* __restrict__ dsum) {
    const int tid = blockIdx.x * 256 + threadIdx.x;
    double s = 0.0;
#pragma unroll 8
    for (int j = 0; j < 43; ++j) {
        float4 v = w4[tid + j * 262144];
        s += (double)(fabsf(v.x) + fabsf(v.y)) + (double)(fabsf(v.z) + fabsf(v.w));
    }
    for (int off = 32; off; off >>= 1) s += __shfl_down(s, off);
    __shared__ double red[4];
    const int lane = threadIdx.x & 63, wv = threadIdx.x >> 6;
    if (lane == 0) red[wv] = s;
    __syncthreads();
    if (threadIdx.x == 0) atomicAdd(dsum, red[0] + red[1] + red[2] + red[3]);
}

__global__ __launch_bounds__(64) void gemm1_k(const float* __restrict__ W,
                                              const float* __restrict__ x,
                                              const double* __restrict__ dsum,
                                              float* __restrict__ dst,
                                              const float* __restrict__ alpha,
                                              const float* __restrict__ bias) {
    const int l = threadIdx.x;
    const int o0 = blockIdx.x * 32;
    const float delta = delta_fix(0.7 * (*dsum) * (1.0 / (double)WCOUNT));
    const int row = l & 31, half = l >> 5;
    const float4* wp = (const float4*)(W + (size_t)(o0 + row) * KDIM + half * 8);
    const float4* xp = (const float4*)(x + (size_t)row * KDIM + half * 8);

    f32x16 acc;
#pragma unroll
    for (int i = 0; i < 16; ++i) acc[i] = 0.0f;

#pragma unroll 8
    for (int s = 0; s < 256; ++s) {
        float4 w0 = wp[s * 4], w1 = wp[s * 4 + 1];
        uint4 bb;
        bb.x = ternpack(w0.x, w0.y, delta);
        bb.y = ternpack(w0.z, w0.w, delta);
        bb.z = ternpack(w1.x, w1.y, delta);
        bb.w = ternpack(w1.z, w1.w, delta);
        float4 v0 = xp[s * 4], v1 = xp[s * 4 + 1];
        struct U { ushort s[8]; } uu;
        uu.s[0] = f2bf(v0.x); uu.s[1] = f2bf(v0.y);
        uu.s[2] = f2bf(v0.z); uu.s[3] = f2bf(v0.w);
        uu.s[4] = f2bf(v1.x); uu.s[5] = f2bf(v1.y);
        uu.s[6] = f2bf(v1.z); uu.s[7] = f2bf(v1.w);
        acc = __builtin_amdgcn_mfma_f32_32x32x16_bf16(
                  __builtin_bit_cast(bf16x8, uu), __builtin_bit_cast(bf16x8, bb),
                  acc, 0, 0, 0);
    }
    const float a = *alpha;
#pragma unroll
    for (int rg = 0; rg < 16; ++rg) {
        const int m = (rg & 3) + 8 * (rg >> 2) + 4 * half;
        const int n = o0 + row;
        dst[(size_t)m * OUTN + n] = fmaf(a, acc[rg], bias[n]);
    }
}

extern "C" void kernel_launch(void* const* d_in, const int* in_sizes, int n_in,
                              void* d_out, int out_size, void* d_ws, size_t ws_size,
                              hipStream_t stream) {
    const float* x     = (const float*)d_in[0];
    const float* W     = (const float*)d_in[1];
    const float* alpha = (const float*)d_in[2];
    const float* bias  = (const float*)d_in[3];
    float* out = (float*)d_out;

    const size_t XB_OFF = 65536;                 // bf16 frags, 256 KB
    const size_t XT_OFF = 393216;                // f32 xT[4096][32], 512 KB
    const size_t CD_OFF = 1u << 20;              // 2-bit codes, 11.25 MB
    const size_t PT_OFF = 16u << 20;             // partials, 4 x 1.4 MB
    const size_t TOTAL  = PT_OFF + 4 * (size_t)BDIM * OUTN * 4;

    if (ws_size >= TOTAL) {
        double* dpart = (double*)d_ws;           // 8 KB partials @ 0
        ushort* xb = (ushort*)((char*)d_ws + XB_OFF);
        float* xT = (float*)((char*)d_ws + XT_OFF);
        unsigned char* codes = (unsigned char*)((char*)d_ws + CD_OFF);
        float* part = (float*)((char*)d_ws + PT_OFF);

        prep_k<<<NPB, 256, 0, stream>>>((const float4*)W, x, xb, xT, codes, dpart);
        gemm32_k<<<NT * 4, 256, 0, stream>>>(W, codes, xb, xT, dpart, part);
        combine_k<<<344, 256, 0, stream>>>((const float4*)part, alpha,
                                           (const float4*)bias, (float4*)out);
    } else {
        double* dsum = (double*)d_ws;
        (void)hipMemsetAsync(d_ws, 0, 16, stream);
        abssum_k<<<1024, 256, 0, stream>>>((const float4*)W, dsum);
        gemm1_k<<<344, 64, 0, stream>>>(W, x, dsum, out, alpha, bias);
    }
}